// Round 4
// baseline (53.339 us; speedup 1.0000x reference)
//
#include <hip/hip_runtime.h>

#define K_SAMP 256
#define D_HID 64
#define SCALER_FE 7.0f

// One ray per wave64, 4 samples per lane. Block = 256 threads = 4 rays.
// No LDS, no __syncthreads: scan and reductions are wave-local.
__global__ __launch_bounds__(256, 4)
void volrend_kernel(const float* __restrict__ ray_start,
                    const float* __restrict__ ray_dir,
                    const float* __restrict__ depth,
                    const float* __restrict__ dists,
                    const int*   __restrict__ vidx,
                    const float* __restrict__ vcol_tab,
                    const float* __restrict__ W1,
                    const float* __restrict__ b1,
                    const float* __restrict__ w_sigma,
                    const float* __restrict__ b_sigma,
                    const float* __restrict__ W_tex,
                    const float* __restrict__ b_tex,
                    float* __restrict__ out_colors,
                    float* __restrict__ out_depths,
                    float* __restrict__ out_missed,
                    float* __restrict__ out_probs) {
    const int lane = threadIdx.x & 63;
    const int wv   = threadIdx.x >> 6;              // 0..3
    // wave-uniform ray id -> scalar loads for per-ray data
    const int ray  = __builtin_amdgcn_readfirstlane(blockIdx.x * 4 + wv);

    const float rs0 = ray_start[ray * 3 + 0];
    const float rs1 = ray_start[ray * 3 + 1];
    const float rs2 = ray_start[ray * 3 + 2];
    const float rd0 = ray_dir[ray * 3 + 0];
    const float rd1 = ray_dir[ray * 3 + 1];
    const float rd2 = ray_dir[ray * 3 + 2];

    // --- per-sample inputs, 4 per lane, vectorized ---
    const float4 dep = ((const float4*)(depth + (size_t)ray * K_SAMP))[lane];
    const float4 dst = ((const float4*)(dists + (size_t)ray * K_SAMP))[lane];
    const int4   vi  = ((const int4*)(vidx  + (size_t)ray * K_SAMP))[lane];

    const float depa[4] = {dep.x, dep.y, dep.z, dep.w};
    const float dsta[4] = {dst.x, dst.y, dst.z, dst.w};
    const int   via[4]  = {vi.x, vi.y, vi.z, vi.w};

    // voxel-color gather issued early (L2-resident table), masked via safe idx
    float vc[4][3];
    bool  msk[4];
    #pragma unroll
    for (int s = 0; s < 4; ++s) {
        msk[s] = (via[s] != -1);
        const int b = (msk[s] ? via[s] : 0) * 3;
        vc[s][0] = vcol_tab[b + 0];
        vc[s][1] = vcol_tab[b + 1];
        vc[s][2] = vcol_tab[b + 2];
    }

    // feat xyz per sample
    float fx[4], fy[4], fz[4];
    #pragma unroll
    for (int s = 0; s < 4; ++s) {
        fx[s] = rs0 + rd0 * depa[s];
        fy[s] = rs1 + rd1 * depa[s];
        fz[s] = rs2 + rd2 * depa[s];
    }

    // --- tiny MLP, 4 independent sample-chains per lane ---
    const float bs = b_sigma[0];
    const float bt0 = b_tex[0], bt1 = b_tex[1], bt2 = b_tex[2];
    float sig[4], t0[4], t1[4], t2[4];
    #pragma unroll
    for (int s = 0; s < 4; ++s) { sig[s] = bs; t0[s] = bt0; t1[s] = bt1; t2[s] = bt2; }

    #pragma unroll 16
    for (int d = 0; d < D_HID; ++d) {
        const float w10 = W1[0 * D_HID + d];
        const float w11 = W1[1 * D_HID + d];
        const float w12 = W1[2 * D_HID + d];
        const float w13 = W1[3 * D_HID + d];
        const float w14 = W1[4 * D_HID + d];
        const float w15 = W1[5 * D_HID + d];
        const float bb  = b1[d];
        const float ws  = w_sigma[d];
        const float wt0 = W_tex[d * 3 + 0];
        const float wt1 = W_tex[d * 3 + 1];
        const float wt2 = W_tex[d * 3 + 2];
        const float hdir = bb + rd0 * w13 + rd1 * w14 + rd2 * w15; // shared across samples
        #pragma unroll
        for (int s = 0; s < 4; ++s) {
            float h = hdir;
            h = fmaf(fx[s], w10, h);
            h = fmaf(fy[s], w11, h);
            h = fmaf(fz[s], w12, h);
            h = fmaxf(h, 0.0f);
            sig[s] = fmaf(h, ws,  sig[s]);
            t0[s]  = fmaf(h, wt0, t0[s]);
            t1[s]  = fmaf(h, wt1, t1[s]);
            t2[s]  = fmaf(h, wt2, t2[s]);
        }
    }

    // --- free energy + masked texture ---
    float fe[4];
    #pragma unroll
    for (int s = 0; s < 4; ++s) {
        if (msk[s]) {
            fe[s] = fmaxf(sig[s], 0.0f) * dsta[s] * SCALER_FE;
            t0[s] += vc[s][0];
            t1[s] += vc[s][1];
            t2[s] += vc[s][2];
        } else {
            fe[s] = 0.0f;
            t0[s] = 0.0f; t1[s] = 0.0f; t2[s] = 0.0f;
        }
    }

    // --- exclusive prefix over the ray: thread-local + wave scan ---
    const float T = fe[0] + fe[1] + fe[2] + fe[3];
    float x = T;
    #pragma unroll
    for (int off = 1; off < 64; off <<= 1) {
        float v = __shfl_up(x, off, 64);
        if (lane >= off) x += v;
    }
    float e0 = x - T;                 // exclusive prefix before sample 4*lane
    float e1 = e0 + fe[0];
    float e2 = e1 + fe[1];
    float e3 = e2 + fe[2];

    const float p0 = (1.0f - __expf(-fe[0])) * __expf(-e0);
    const float p1 = (1.0f - __expf(-fe[1])) * __expf(-e1);
    const float p2 = (1.0f - __expf(-fe[2])) * __expf(-e2);
    const float p3 = (1.0f - __expf(-fe[3])) * __expf(-e3);

    // --- wave reductions ---
    float sp = p0 + p1 + p2 + p3;
    float sd = depa[0] * p0 + depa[1] * p1 + depa[2] * p2 + depa[3] * p3;
    float c0 = t0[0] * p0 + t0[1] * p1 + t0[2] * p2 + t0[3] * p3;
    float c1 = t1[0] * p0 + t1[1] * p1 + t1[2] * p2 + t1[3] * p3;
    float c2 = t2[0] * p0 + t2[1] * p1 + t2[2] * p2 + t2[3] * p3;
    #pragma unroll
    for (int off = 32; off > 0; off >>= 1) {
        sp += __shfl_down(sp, off, 64);
        sd += __shfl_down(sd, off, 64);
        c0 += __shfl_down(c0, off, 64);
        c1 += __shfl_down(c1, off, 64);
        c2 += __shfl_down(c2, off, 64);
    }
    if (lane == 0) {
        out_colors[ray * 3 + 0] = c0;
        out_colors[ray * 3 + 1] = c1;
        out_colors[ray * 3 + 2] = c2;
        out_depths[ray] = sd;
        out_missed[ray] = 1.0f - sp;
    }
    ((float4*)(out_probs + (size_t)ray * K_SAMP))[lane] =
        make_float4(p0, p1, p2, p3);
}

extern "C" void kernel_launch(void* const* d_in, const int* in_sizes, int n_in,
                              void* d_out, int out_size, void* d_ws, size_t ws_size,
                              hipStream_t stream) {
    const float* ray_start  = (const float*)d_in[0];
    const float* ray_dir    = (const float*)d_in[1];
    const float* depth      = (const float*)d_in[2];
    const float* dists      = (const float*)d_in[3];
    const int*   vidx       = (const int*)d_in[4];
    const float* vcol       = (const float*)d_in[5];
    const float* W1         = (const float*)d_in[6];
    const float* b1         = (const float*)d_in[7];
    const float* w_sigma    = (const float*)d_in[8];
    const float* b_sigma    = (const float*)d_in[9];
    const float* W_tex      = (const float*)d_in[10];
    const float* b_tex      = (const float*)d_in[11];

    const int N = in_sizes[0] / 3;       // 4096 rays
    // output layout: colors[N*3] | depths[N] | missed[N] | probs[N*K]
    float* out        = (float*)d_out;
    float* out_colors = out;
    float* out_depths = out + (size_t)N * 3;
    float* out_missed = out + (size_t)N * 3 + N;
    float* out_probs  = out + (size_t)N * 3 + 2 * (size_t)N;

    volrend_kernel<<<N / 4, 256, 0, stream>>>(
        ray_start, ray_dir, depth, dists, vidx, vcol,
        W1, b1, w_sigma, b_sigma, W_tex, b_tex,
        out_colors, out_depths, out_missed, out_probs);
}

// Round 5
// 21.920 us; speedup vs baseline: 2.4333x; 2.4333x over previous
//
#include <hip/hip_runtime.h>

#define K_SAMP 256
#define D_HID 64
#define SCALER_FE 7.0f

typedef _Float16 half8 __attribute__((ext_vector_type(8)));
typedef float f32x4 __attribute__((ext_vector_type(4)));

__device__ __forceinline__ half8 h8zero() {
    half8 a;
    #pragma unroll
    for (int j = 0; j < 8; ++j) a[j] = (_Float16)0.f;
    return a;
}

// One ray per wave64. MLP via f16 MFMA (16x16x32), 16 sample-tiles of 16.
// Layer1: h^T[64 dims x 16 samp] = W1^T·feat^T (4 MFMAs, dim-permuted tiles,
//         bias folded at k=6). Layer2: out^T[4 x 16 samp] = W2^T·h (2 MFMAs).
// Dim permutation dim(tile,m)=8*(m>>2)+(m&3)+4*(tile&1)+32*(tile>>1) makes the
// MFMA1 C-layout coincide with MFMA2's B-operand layout: no cross-lane moves.
__global__ __launch_bounds__(256, 4)
void volrend_kernel(const float* __restrict__ ray_start,
                    const float* __restrict__ ray_dir,
                    const float* __restrict__ depth,
                    const float* __restrict__ dists,
                    const int*   __restrict__ vidx,
                    const float* __restrict__ vcol_tab,
                    const float* __restrict__ W1,
                    const float* __restrict__ b1,
                    const float* __restrict__ w_sigma,
                    const float* __restrict__ b_sigma,
                    const float* __restrict__ W_tex,
                    const float* __restrict__ b_tex,
                    float* __restrict__ out_colors,
                    float* __restrict__ out_depths,
                    float* __restrict__ out_missed,
                    float* __restrict__ out_probs) {
    __shared__ float lds[4][K_SAMP][4];     // 16 KB: {sigma,t0,t1,t2}/sample

    const int lane = threadIdx.x & 63;
    const int wv   = threadIdx.x >> 6;
    const int ray  = __builtin_amdgcn_readfirstlane(blockIdx.x * 4 + wv);
    const int m    = lane & 15;             // M/N index inside MFMA tile
    const int g    = lane >> 4;             // K-slice lane group

    // --- per-ray uniforms ---
    const float rs0 = ray_start[ray * 3 + 0];
    const float rs1 = ray_start[ray * 3 + 1];
    const float rs2 = ray_start[ray * 3 + 2];
    const float rd0 = ray_dir[ray * 3 + 0];
    const float rd1 = ray_dir[ray * 3 + 1];
    const float rd2 = ray_dir[ray * 3 + 2];
    const float bs  = b_sigma[0];
    const float bt0 = b_tex[0], bt1 = b_tex[1], bt2 = b_tex[2];

    // --- A1 fragments: W1^T with permuted dim order; b1 folded at k=6 ---
    half8 a1[4];
    #pragma unroll
    for (int tt = 0; tt < 4; ++tt) {
        const int dim = 8 * (m >> 2) + (m & 3) + 4 * (tt & 1) + 32 * (tt >> 1);
        half8 a = h8zero();
        if (g == 0) {
            #pragma unroll
            for (int j = 0; j < 6; ++j) a[j] = (_Float16)W1[j * D_HID + dim];
            a[6] = (_Float16)b1[dim];
        }
        a1[tt] = a;
    }

    // --- A2 fragments: W2^T rows {sigma, tex0..2}, k = true dim index ---
    half8 a2a = h8zero(), a2b = h8zero();
    if (m < 4) {
        const int c = (m >= 1) ? (m - 1) : 0;
        #pragma unroll
        for (int j = 0; j < 8; ++j) {
            const int d = 8 * g + j;
            const float va = (m == 0) ? w_sigma[d]      : W_tex[d * 3 + c];
            const float vb = (m == 0) ? w_sigma[d + 32] : W_tex[(d + 32) * 3 + c];
            a2a[j] = (_Float16)va;
            a2b[j] = (_Float16)vb;
        }
    }

    // --- per-lane owned samples (epilogue), issued early ---
    const size_t rayBase = (size_t)ray * K_SAMP;
    const float4 dep = ((const float4*)(depth + rayBase))[lane];
    const float4 dst = ((const float4*)(dists + rayBase))[lane];
    const int4   vi  = ((const int4*)(vidx  + rayBase))[lane];
    const float depa[4] = {dep.x, dep.y, dep.z, dep.w};
    const float dsta[4] = {dst.x, dst.y, dst.z, dst.w};
    const int   via[4]  = {vi.x, vi.y, vi.z, vi.w};
    float vc[4][3];
    bool  msk[4];
    #pragma unroll
    for (int s = 0; s < 4; ++s) {
        msk[s] = (via[s] != -1);
        const int b = (msk[s] ? via[s] : 0) * 3;
        vc[s][0] = vcol_tab[b + 0];
        vc[s][1] = vcol_tab[b + 1];
        vc[s][2] = vcol_tab[b + 2];
    }

    f32x4 oinit = {0.f, 0.f, 0.f, 0.f};
    if (g == 0) { oinit[0] = bs; oinit[1] = bt0; oinit[2] = bt1; oinit[3] = bt2; }
    const f32x4 zero4 = {0.f, 0.f, 0.f, 0.f};

    // --- 16 sample-tiles of 16 ---
    #pragma unroll 2
    for (int t = 0; t < 16; ++t) {
        const float dpt = depth[rayBase + 16 * t + m];
        const float fx = fmaf(rd0, dpt, rs0);
        const float fy = fmaf(rd1, dpt, rs1);
        const float fz = fmaf(rd2, dpt, rs2);
        half8 b1f = h8zero();
        if (g == 0) {
            b1f[0] = (_Float16)fx;  b1f[1] = (_Float16)fy;  b1f[2] = (_Float16)fz;
            b1f[3] = (_Float16)rd0; b1f[4] = (_Float16)rd1; b1f[5] = (_Float16)rd2;
            b1f[6] = (_Float16)1.0f;
        }
        f32x4 h0 = __builtin_amdgcn_mfma_f32_16x16x32_f16(a1[0], b1f, zero4, 0, 0, 0);
        f32x4 h1 = __builtin_amdgcn_mfma_f32_16x16x32_f16(a1[1], b1f, zero4, 0, 0, 0);
        f32x4 h2 = __builtin_amdgcn_mfma_f32_16x16x32_f16(a1[2], b1f, zero4, 0, 0, 0);
        f32x4 h3 = __builtin_amdgcn_mfma_f32_16x16x32_f16(a1[3], b1f, zero4, 0, 0, 0);

        half8 b2a, b2b;
        #pragma unroll
        for (int r = 0; r < 4; ++r) {
            b2a[r]     = (_Float16)fmaxf(h0[r], 0.f);
            b2a[r + 4] = (_Float16)fmaxf(h1[r], 0.f);
            b2b[r]     = (_Float16)fmaxf(h2[r], 0.f);
            b2b[r + 4] = (_Float16)fmaxf(h3[r], 0.f);
        }
        f32x4 o = oinit;
        o = __builtin_amdgcn_mfma_f32_16x16x32_f16(a2a, b2a, o, 0, 0, 0);
        o = __builtin_amdgcn_mfma_f32_16x16x32_f16(a2b, b2b, o, 0, 0, 0);

        if (g == 0) {
            *(float4*)&lds[wv][16 * t + m][0] = make_float4(o[0], o[1], o[2], o[3]);
        }
    }
    __syncthreads();

    // --- epilogue: lane owns samples 4*lane..4*lane+3 (R4-verified path) ---
    float sg[4], tA[4], tB[4], tC[4];
    #pragma unroll
    for (int c = 0; c < 4; ++c) {
        const float4 r = *(const float4*)&lds[wv][4 * lane + c][0];
        sg[c] = r.x; tA[c] = r.y; tB[c] = r.z; tC[c] = r.w;
    }

    float fe[4];
    #pragma unroll
    for (int s = 0; s < 4; ++s) {
        if (msk[s]) {
            fe[s] = fmaxf(sg[s], 0.0f) * dsta[s] * SCALER_FE;
            tA[s] += vc[s][0];
            tB[s] += vc[s][1];
            tC[s] += vc[s][2];
        } else {
            fe[s] = 0.0f;
            tA[s] = 0.0f; tB[s] = 0.0f; tC[s] = 0.0f;
        }
    }

    const float T = fe[0] + fe[1] + fe[2] + fe[3];
    float x = T;
    #pragma unroll
    for (int off = 1; off < 64; off <<= 1) {
        float v = __shfl_up(x, off, 64);
        if (lane >= off) x += v;
    }
    float e0 = x - T;
    float e1 = e0 + fe[0];
    float e2 = e1 + fe[1];
    float e3 = e2 + fe[2];

    const float p0 = (1.0f - __expf(-fe[0])) * __expf(-e0);
    const float p1 = (1.0f - __expf(-fe[1])) * __expf(-e1);
    const float p2 = (1.0f - __expf(-fe[2])) * __expf(-e2);
    const float p3 = (1.0f - __expf(-fe[3])) * __expf(-e3);

    float sp = p0 + p1 + p2 + p3;
    float sd = depa[0] * p0 + depa[1] * p1 + depa[2] * p2 + depa[3] * p3;
    float c0 = tA[0] * p0 + tA[1] * p1 + tA[2] * p2 + tA[3] * p3;
    float c1 = tB[0] * p0 + tB[1] * p1 + tB[2] * p2 + tB[3] * p3;
    float c2 = tC[0] * p0 + tC[1] * p1 + tC[2] * p2 + tC[3] * p3;
    #pragma unroll
    for (int off = 32; off > 0; off >>= 1) {
        sp += __shfl_down(sp, off, 64);
        sd += __shfl_down(sd, off, 64);
        c0 += __shfl_down(c0, off, 64);
        c1 += __shfl_down(c1, off, 64);
        c2 += __shfl_down(c2, off, 64);
    }
    if (lane == 0) {
        out_colors[ray * 3 + 0] = c0;
        out_colors[ray * 3 + 1] = c1;
        out_colors[ray * 3 + 2] = c2;
        out_depths[ray] = sd;
        out_missed[ray] = 1.0f - sp;
    }
    ((float4*)(out_probs + rayBase))[lane] = make_float4(p0, p1, p2, p3);
}

extern "C" void kernel_launch(void* const* d_in, const int* in_sizes, int n_in,
                              void* d_out, int out_size, void* d_ws, size_t ws_size,
                              hipStream_t stream) {
    const float* ray_start  = (const float*)d_in[0];
    const float* ray_dir    = (const float*)d_in[1];
    const float* depth      = (const float*)d_in[2];
    const float* dists      = (const float*)d_in[3];
    const int*   vidx       = (const int*)d_in[4];
    const float* vcol       = (const float*)d_in[5];
    const float* W1         = (const float*)d_in[6];
    const float* b1         = (const float*)d_in[7];
    const float* w_sigma    = (const float*)d_in[8];
    const float* b_sigma    = (const float*)d_in[9];
    const float* W_tex      = (const float*)d_in[10];
    const float* b_tex      = (const float*)d_in[11];

    const int N = in_sizes[0] / 3;       // 4096 rays
    float* out        = (float*)d_out;
    float* out_colors = out;
    float* out_depths = out + (size_t)N * 3;
    float* out_missed = out + (size_t)N * 3 + N;
    float* out_probs  = out + (size_t)N * 3 + 2 * (size_t)N;

    volrend_kernel<<<N / 4, 256, 0, stream>>>(
        ray_start, ray_dir, depth, dists, vidx, vcol,
        W1, b1, w_sigma, b_sigma, W_tex, b_tex,
        out_colors, out_depths, out_missed, out_probs);
}

// Round 6
// 21.092 us; speedup vs baseline: 2.5289x; 1.0393x over previous
//
#include <hip/hip_runtime.h>

#define K_SAMP 256
#define D_HID 64
#define SCALER_FE 7.0f

typedef _Float16 half8 __attribute__((ext_vector_type(8)));
typedef float f32x4 __attribute__((ext_vector_type(4)));

__device__ __forceinline__ half8 h8zero() {
    half8 a;
    #pragma unroll
    for (int j = 0; j < 8; ++j) a[j] = (_Float16)0.f;
    return a;
}

// Two waves per ray (128 samples / 8 tiles each); block = 4 waves = 2 rays.
// MLP per tile: 4x mfma_f32_16x16x32_f16 (layer1, dim-permuted, bias at k=6)
// + 2x (layer2). Cross-wave coupling: half-0's fe total via LDS; 5 reductions
// combined via LDS. Grid = N/2 = 2048 blocks -> 8192 waves for TLP.
__global__ __launch_bounds__(256, 8)
void volrend_kernel(const float* __restrict__ ray_start,
                    const float* __restrict__ ray_dir,
                    const float* __restrict__ depth,
                    const float* __restrict__ dists,
                    const int*   __restrict__ vidx,
                    const float* __restrict__ vcol_tab,
                    const float* __restrict__ W1,
                    const float* __restrict__ b1,
                    const float* __restrict__ w_sigma,
                    const float* __restrict__ b_sigma,
                    const float* __restrict__ W_tex,
                    const float* __restrict__ b_tex,
                    float* __restrict__ out_colors,
                    float* __restrict__ out_depths,
                    float* __restrict__ out_missed,
                    float* __restrict__ out_probs) {
    __shared__ float sOut[2][K_SAMP][4];   // 8 KB: {sigma,t0,t1,t2}/sample
    __shared__ float sHtot[2];             // half-0 fe totals per local ray
    __shared__ float sRed[2][2][5];        // per-wave reduction partials

    const int lane = threadIdx.x & 63;
    const int wv   = threadIdx.x >> 6;
    const int r    = wv >> 1;                      // local ray 0/1
    const int half = __builtin_amdgcn_readfirstlane(wv & 1);
    const int ray  = __builtin_amdgcn_readfirstlane(blockIdx.x * 2 + r);
    const int m    = lane & 15;                    // index inside MFMA tile
    const int g    = lane >> 4;                    // K-slice lane group

    // --- per-ray uniforms ---
    const float rs0 = ray_start[ray * 3 + 0];
    const float rs1 = ray_start[ray * 3 + 1];
    const float rs2 = ray_start[ray * 3 + 2];
    const float rd0 = ray_dir[ray * 3 + 0];
    const float rd1 = ray_dir[ray * 3 + 1];
    const float rd2 = ray_dir[ray * 3 + 2];
    const float bs  = b_sigma[0];
    const float bt0 = b_tex[0], bt1 = b_tex[1], bt2 = b_tex[2];

    // --- A1 fragments: W1^T, permuted dim order; b1 folded at k=6 ---
    half8 a1[4];
    #pragma unroll
    for (int tt = 0; tt < 4; ++tt) {
        const int dim = 8 * (m >> 2) + (m & 3) + 4 * (tt & 1) + 32 * (tt >> 1);
        half8 a = h8zero();
        if (g == 0) {
            #pragma unroll
            for (int j = 0; j < 6; ++j) a[j] = (_Float16)W1[j * D_HID + dim];
            a[6] = (_Float16)b1[dim];
        }
        a1[tt] = a;
    }

    // --- A2 fragments: rows {sigma, tex0..2} of W2^T ---
    half8 a2a = h8zero(), a2b = h8zero();
    if (m < 4) {
        const int c = (m >= 1) ? (m - 1) : 0;
        #pragma unroll
        for (int j = 0; j < 8; ++j) {
            const int d = 8 * g + j;
            const float va = (m == 0) ? w_sigma[d]      : W_tex[d * 3 + c];
            const float vb = (m == 0) ? w_sigma[d + 32] : W_tex[(d + 32) * 3 + c];
            a2a[j] = (_Float16)va;
            a2b[j] = (_Float16)vb;
        }
    }

    f32x4 oinit = {0.f, 0.f, 0.f, 0.f};
    if (g == 0) { oinit[0] = bs; oinit[1] = bt0; oinit[2] = bt1; oinit[3] = bt2; }
    const f32x4 zero4 = {0.f, 0.f, 0.f, 0.f};

    const size_t rayBase  = (size_t)ray * K_SAMP;
    const size_t halfBase = rayBase + half * 128;

    // --- 8 sample-tiles of 16 for this wave's half ---
    #pragma unroll 2
    for (int t = 0; t < 8; ++t) {
        const float dpt = depth[halfBase + 16 * t + m];
        const float fx = fmaf(rd0, dpt, rs0);
        const float fy = fmaf(rd1, dpt, rs1);
        const float fz = fmaf(rd2, dpt, rs2);
        half8 b1f = h8zero();
        if (g == 0) {
            b1f[0] = (_Float16)fx;  b1f[1] = (_Float16)fy;  b1f[2] = (_Float16)fz;
            b1f[3] = (_Float16)rd0; b1f[4] = (_Float16)rd1; b1f[5] = (_Float16)rd2;
            b1f[6] = (_Float16)1.0f;
        }
        f32x4 h0 = __builtin_amdgcn_mfma_f32_16x16x32_f16(a1[0], b1f, zero4, 0, 0, 0);
        f32x4 h1 = __builtin_amdgcn_mfma_f32_16x16x32_f16(a1[1], b1f, zero4, 0, 0, 0);
        f32x4 h2 = __builtin_amdgcn_mfma_f32_16x16x32_f16(a1[2], b1f, zero4, 0, 0, 0);
        f32x4 h3 = __builtin_amdgcn_mfma_f32_16x16x32_f16(a1[3], b1f, zero4, 0, 0, 0);

        half8 b2a, b2b;
        #pragma unroll
        for (int rr = 0; rr < 4; ++rr) {
            b2a[rr]     = (_Float16)fmaxf(h0[rr], 0.f);
            b2a[rr + 4] = (_Float16)fmaxf(h1[rr], 0.f);
            b2b[rr]     = (_Float16)fmaxf(h2[rr], 0.f);
            b2b[rr + 4] = (_Float16)fmaxf(h3[rr], 0.f);
        }
        f32x4 o = oinit;
        o = __builtin_amdgcn_mfma_f32_16x16x32_f16(a2a, b2a, o, 0, 0, 0);
        o = __builtin_amdgcn_mfma_f32_16x16x32_f16(a2b, b2b, o, 0, 0, 0);

        if (g == 0) {
            *(float4*)&sOut[r][half * 128 + 16 * t + m][0] =
                make_float4(o[0], o[1], o[2], o[3]);
        }
    }

    // --- epilogue: lane owns 2 samples of its half (same-wave LDS data) ---
    const float2 dep = ((const float2*)(depth + halfBase))[lane];
    const float2 dst = ((const float2*)(dists + halfBase))[lane];
    const int2   vi  = ((const int2*)(vidx  + halfBase))[lane];
    const bool msk0 = (vi.x != -1);
    const bool msk1 = (vi.y != -1);
    const int  vb0  = (msk0 ? vi.x : 0) * 3;
    const int  vb1  = (msk1 ? vi.y : 0) * 3;
    const float vcx0 = vcol_tab[vb0 + 0], vcy0 = vcol_tab[vb0 + 1], vcz0 = vcol_tab[vb0 + 2];
    const float vcx1 = vcol_tab[vb1 + 0], vcy1 = vcol_tab[vb1 + 1], vcz1 = vcol_tab[vb1 + 2];

    const int sIdx = half * 128 + 2 * lane;
    const float4 r0 = *(const float4*)&sOut[r][sIdx][0];
    const float4 r1 = *(const float4*)&sOut[r][sIdx + 1][0];

    float fe0 = 0.f, fe1 = 0.f;
    float tA0 = 0.f, tB0 = 0.f, tC0 = 0.f;
    float tA1 = 0.f, tB1 = 0.f, tC1 = 0.f;
    if (msk0) {
        fe0 = fmaxf(r0.x, 0.f) * dst.x * SCALER_FE;
        tA0 = r0.y + vcx0; tB0 = r0.z + vcy0; tC0 = r0.w + vcz0;
    }
    if (msk1) {
        fe1 = fmaxf(r1.x, 0.f) * dst.y * SCALER_FE;
        tA1 = r1.y + vcx1; tB1 = r1.z + vcy1; tC1 = r1.w + vcz1;
    }

    // wave scan over this half (lane order == sample order)
    const float T = fe0 + fe1;
    float x = T;
    #pragma unroll
    for (int off = 1; off < 64; off <<= 1) {
        float v = __shfl_up(x, off, 64);
        if (lane >= off) x += v;
    }
    if (half == 0 && lane == 63) sHtot[r] = x;   // total fe of first half
    __syncthreads();

    const float base = half ? sHtot[r] : 0.0f;
    const float e0 = base + x - T;
    const float e1 = e0 + fe0;

    const float p0 = (1.0f - __expf(-fe0)) * __expf(-e0);
    const float p1 = (1.0f - __expf(-fe1)) * __expf(-e1);

    // wave-level partial reductions over this half
    float sp = p0 + p1;
    float sd = dep.x * p0 + dep.y * p1;
    float c0 = tA0 * p0 + tA1 * p1;
    float c1 = tB0 * p0 + tB1 * p1;
    float c2 = tC0 * p0 + tC1 * p1;
    #pragma unroll
    for (int off = 32; off > 0; off >>= 1) {
        sp += __shfl_down(sp, off, 64);
        sd += __shfl_down(sd, off, 64);
        c0 += __shfl_down(c0, off, 64);
        c1 += __shfl_down(c1, off, 64);
        c2 += __shfl_down(c2, off, 64);
    }
    if (lane == 0) {
        sRed[r][half][0] = sp;
        sRed[r][half][1] = sd;
        sRed[r][half][2] = c0;
        sRed[r][half][3] = c1;
        sRed[r][half][4] = c2;
    }

    ((float2*)(out_probs + halfBase))[lane] = make_float2(p0, p1);

    __syncthreads();
    if (half == 0 && lane == 0) {
        const float tp  = sRed[r][0][0] + sRed[r][1][0];
        const float td  = sRed[r][0][1] + sRed[r][1][1];
        const float tc0 = sRed[r][0][2] + sRed[r][1][2];
        const float tc1 = sRed[r][0][3] + sRed[r][1][3];
        const float tc2 = sRed[r][0][4] + sRed[r][1][4];
        out_colors[ray * 3 + 0] = tc0;
        out_colors[ray * 3 + 1] = tc1;
        out_colors[ray * 3 + 2] = tc2;
        out_depths[ray] = td;
        out_missed[ray] = 1.0f - tp;
    }
}

extern "C" void kernel_launch(void* const* d_in, const int* in_sizes, int n_in,
                              void* d_out, int out_size, void* d_ws, size_t ws_size,
                              hipStream_t stream) {
    const float* ray_start  = (const float*)d_in[0];
    const float* ray_dir    = (const float*)d_in[1];
    const float* depth      = (const float*)d_in[2];
    const float* dists      = (const float*)d_in[3];
    const int*   vidx       = (const int*)d_in[4];
    const float* vcol       = (const float*)d_in[5];
    const float* W1         = (const float*)d_in[6];
    const float* b1         = (const float*)d_in[7];
    const float* w_sigma    = (const float*)d_in[8];
    const float* b_sigma    = (const float*)d_in[9];
    const float* W_tex      = (const float*)d_in[10];
    const float* b_tex      = (const float*)d_in[11];

    const int N = in_sizes[0] / 3;       // 4096 rays
    float* out        = (float*)d_out;
    float* out_colors = out;
    float* out_depths = out + (size_t)N * 3;
    float* out_missed = out + (size_t)N * 3 + N;
    float* out_probs  = out + (size_t)N * 3 + 2 * (size_t)N;

    volrend_kernel<<<N / 2, 256, 0, stream>>>(
        ray_start, ray_dir, depth, dists, vidx, vcol,
        W1, b1, w_sigma, b_sigma, W_tex, b_tex,
        out_colors, out_depths, out_missed, out_probs);
}

// Round 8
// 21.046 us; speedup vs baseline: 2.5344x; 1.0022x over previous
//
#include <hip/hip_runtime.h>

#define K_SAMP 256
#define D_HID 64
#define SCALER_FE 7.0f

typedef _Float16 half8  __attribute__((ext_vector_type(8)));
typedef __fp16   fp16x2 __attribute__((ext_vector_type(2)));
typedef float    f32x4  __attribute__((ext_vector_type(4)));

union H8U4 { half8 h; uint4 u; };
union H8P  { fp16x2 h2[4]; half8 h8; };

__device__ __forceinline__ half8 h8zero() {
    half8 a;
    #pragma unroll
    for (int j = 0; j < 8; ++j) a[j] = (_Float16)0.f;
    return a;
}

// Block = 1 ray = 4 waves; each wave computes 64 samples (4 MFMA tiles of 16).
// Wave 0 builds the lane-indexed (ray-independent) f16 weight fragments into
// LDS once per block; all waves fetch them with 6 coalesced b128 LDS reads.
// Layer1: 4x mfma_f32_16x16x32_f16 (dim-permuted, bias at k=6); layer2: 2x.
// Scan couples 4 waves via sTot; reductions via sRed.
__global__ __launch_bounds__(256, 6)
void volrend_kernel(const float* __restrict__ ray_start,
                    const float* __restrict__ ray_dir,
                    const float* __restrict__ depth,
                    const float* __restrict__ dists,
                    const int*   __restrict__ vidx,
                    const float* __restrict__ vcol_tab,
                    const float* __restrict__ W1,
                    const float* __restrict__ b1,
                    const float* __restrict__ w_sigma,
                    const float* __restrict__ b_sigma,
                    const float* __restrict__ W_tex,
                    const float* __restrict__ b_tex,
                    float* __restrict__ out_colors,
                    float* __restrict__ out_depths,
                    float* __restrict__ out_missed,
                    float* __restrict__ out_probs) {
    __shared__ uint4 sFrag[6 * 64];        // 6 KB: a1[0..3], a2a, a2b per lane
    __shared__ float sOut[K_SAMP][4];      // 4 KB: {sigma,t0,t1,t2}/sample
    __shared__ float sTot[4];              // per-wave fe totals
    __shared__ float sRed[4][5];           // per-wave reduction partials

    const int tid  = threadIdx.x;
    const int lane = tid & 63;
    const int wv   = tid >> 6;
    const int ray  = blockIdx.x;
    const int m    = lane & 15;            // sample index inside MFMA tile
    const int g    = lane >> 4;            // K-slice lane group

    // --- wave 0: build fragments into LDS (ray-independent, lane-indexed) ---
    if (tid < 64) {
        #pragma unroll
        for (int tt = 0; tt < 4; ++tt) {
            const int dim = 8 * (m >> 2) + (m & 3) + 4 * (tt & 1) + 32 * (tt >> 1);
            half8 a = h8zero();
            if (g == 0) {
                #pragma unroll
                for (int j = 0; j < 6; ++j) a[j] = (_Float16)W1[j * D_HID + dim];
                a[6] = (_Float16)b1[dim];
            }
            H8U4 c; c.h = a;
            sFrag[tt * 64 + lane] = c.u;
        }
        half8 a2a = h8zero(), a2b = h8zero();
        if (m < 4) {
            const int c = (m >= 1) ? (m - 1) : 0;
            #pragma unroll
            for (int j = 0; j < 8; ++j) {
                const int d = 8 * g + j;
                a2a[j] = (_Float16)((m == 0) ? w_sigma[d]      : W_tex[d * 3 + c]);
                a2b[j] = (_Float16)((m == 0) ? w_sigma[d + 32] : W_tex[(d + 32) * 3 + c]);
            }
        }
        H8U4 ca; ca.h = a2a; sFrag[4 * 64 + lane] = ca.u;
        H8U4 cb; cb.h = a2b; sFrag[5 * 64 + lane] = cb.u;
    }

    // --- per-ray uniforms (ray == blockIdx.x -> scalar loads) ---
    const float rs0 = ray_start[ray * 3 + 0];
    const float rs1 = ray_start[ray * 3 + 1];
    const float rs2 = ray_start[ray * 3 + 2];
    const float rd0 = ray_dir[ray * 3 + 0];
    const float rd1 = ray_dir[ray * 3 + 1];
    const float rd2 = ray_dir[ray * 3 + 2];
    const float bs  = b_sigma[0];
    const float bt0 = b_tex[0], bt1 = b_tex[1], bt2 = b_tex[2];

    __syncthreads();

    half8 a1[4];
    #pragma unroll
    for (int tt = 0; tt < 4; ++tt) { H8U4 c; c.u = sFrag[tt * 64 + lane]; a1[tt] = c.h; }
    H8U4 ca; ca.u = sFrag[4 * 64 + lane]; const half8 a2a = ca.h;
    H8U4 cb; cb.u = sFrag[5 * 64 + lane]; const half8 a2b = cb.h;

    f32x4 oinit = {0.f, 0.f, 0.f, 0.f};
    if (g == 0) { oinit[0] = bs; oinit[1] = bt0; oinit[2] = bt1; oinit[3] = bt2; }
    const f32x4 zero4 = {0.f, 0.f, 0.f, 0.f};

    // constant halves of the B1 operand
    const fp16x2 hc12 = __builtin_amdgcn_cvt_pkrtz(rd1, rd2);
    const fp16x2 hc3  = __builtin_amdgcn_cvt_pkrtz(1.0f, 0.0f);

    const size_t rayBase = (size_t)ray * K_SAMP;
    const int    qBase   = wv * 64;        // this wave's sample offset

    // --- 4 sample-tiles of 16 ---
    #pragma unroll
    for (int t = 0; t < 4; ++t) {
        const float dpt = depth[rayBase + qBase + 16 * t + m];
        const float fx = fmaf(rd0, dpt, rs0);
        const float fy = fmaf(rd1, dpt, rs1);
        const float fz = fmaf(rd2, dpt, rs2);
        H8P bb;
        bb.h2[0] = __builtin_amdgcn_cvt_pkrtz(fx, fy);
        bb.h2[1] = __builtin_amdgcn_cvt_pkrtz(fz, rd0);
        bb.h2[2] = hc12;
        bb.h2[3] = hc3;
        const f32x4 h0 = __builtin_amdgcn_mfma_f32_16x16x32_f16(a1[0], bb.h8, zero4, 0, 0, 0);
        const f32x4 h1 = __builtin_amdgcn_mfma_f32_16x16x32_f16(a1[1], bb.h8, zero4, 0, 0, 0);
        const f32x4 h2 = __builtin_amdgcn_mfma_f32_16x16x32_f16(a1[2], bb.h8, zero4, 0, 0, 0);
        const f32x4 h3 = __builtin_amdgcn_mfma_f32_16x16x32_f16(a1[3], bb.h8, zero4, 0, 0, 0);

        H8P p2a, p2b;
        p2a.h2[0] = __builtin_amdgcn_cvt_pkrtz(fmaxf(h0[0], 0.f), fmaxf(h0[1], 0.f));
        p2a.h2[1] = __builtin_amdgcn_cvt_pkrtz(fmaxf(h0[2], 0.f), fmaxf(h0[3], 0.f));
        p2a.h2[2] = __builtin_amdgcn_cvt_pkrtz(fmaxf(h1[0], 0.f), fmaxf(h1[1], 0.f));
        p2a.h2[3] = __builtin_amdgcn_cvt_pkrtz(fmaxf(h1[2], 0.f), fmaxf(h1[3], 0.f));
        p2b.h2[0] = __builtin_amdgcn_cvt_pkrtz(fmaxf(h2[0], 0.f), fmaxf(h2[1], 0.f));
        p2b.h2[1] = __builtin_amdgcn_cvt_pkrtz(fmaxf(h2[2], 0.f), fmaxf(h2[3], 0.f));
        p2b.h2[2] = __builtin_amdgcn_cvt_pkrtz(fmaxf(h3[0], 0.f), fmaxf(h3[1], 0.f));
        p2b.h2[3] = __builtin_amdgcn_cvt_pkrtz(fmaxf(h3[2], 0.f), fmaxf(h3[3], 0.f));

        f32x4 o = oinit;
        o = __builtin_amdgcn_mfma_f32_16x16x32_f16(a2a, p2a.h8, o, 0, 0, 0);
        o = __builtin_amdgcn_mfma_f32_16x16x32_f16(a2b, p2b.h8, o, 0, 0, 0);

        if (g == 0) {
            *(float4*)&sOut[qBase + 16 * t + m][0] = make_float4(o[0], o[1], o[2], o[3]);
        }
    }
    __syncthreads();

    // --- epilogue: lane owns exactly sample `tid` ---
    const float dep = depth[rayBase + tid];
    const float dst = dists[rayBase + tid];
    const int   vi  = vidx[rayBase + tid];
    const bool  msk = (vi != -1);
    const int   vb  = (msk ? vi : 0) * 3;
    const float vc0 = vcol_tab[vb + 0];
    const float vc1 = vcol_tab[vb + 1];
    const float vc2 = vcol_tab[vb + 2];

    const float4 r4 = *(const float4*)&sOut[tid][0];
    float fe = 0.f, tA = 0.f, tB = 0.f, tC = 0.f;
    if (msk) {
        fe = fmaxf(r4.x, 0.f) * dst * SCALER_FE;
        tA = r4.y + vc0; tB = r4.z + vc1; tC = r4.w + vc2;
    }

    // wave-inclusive scan of fe, then cross-wave exclusive base
    float x = fe;
    #pragma unroll
    for (int off = 1; off < 64; off <<= 1) {
        float v = __shfl_up(x, off, 64);
        if (lane >= off) x += v;
    }
    if (lane == 63) sTot[wv] = x;
    __syncthreads();
    float base = 0.f;
    #pragma unroll
    for (int w = 0; w < 3; ++w) {
        if (w < wv) base += sTot[w];
    }
    const float e0 = base + x - fe;
    const float p  = (1.0f - __expf(-fe)) * __expf(-e0);
    out_probs[rayBase + tid] = p;

    float sp = p;
    float sd = dep * p;
    float c0 = tA * p;
    float c1 = tB * p;
    float c2 = tC * p;
    #pragma unroll
    for (int off = 32; off > 0; off >>= 1) {
        sp += __shfl_down(sp, off, 64);
        sd += __shfl_down(sd, off, 64);
        c0 += __shfl_down(c0, off, 64);
        c1 += __shfl_down(c1, off, 64);
        c2 += __shfl_down(c2, off, 64);
    }
    if (lane == 0) {
        sRed[wv][0] = sp;
        sRed[wv][1] = sd;
        sRed[wv][2] = c0;
        sRed[wv][3] = c1;
        sRed[wv][4] = c2;
    }
    __syncthreads();
    if (tid < 5) {
        const float v = sRed[0][tid] + sRed[1][tid] + sRed[2][tid] + sRed[3][tid];
        if (tid == 0)      out_missed[ray] = 1.0f - v;
        else if (tid == 1) out_depths[ray] = v;
        else               out_colors[ray * 3 + (tid - 2)] = v;
    }
}

extern "C" void kernel_launch(void* const* d_in, const int* in_sizes, int n_in,
                              void* d_out, int out_size, void* d_ws, size_t ws_size,
                              hipStream_t stream) {
    const float* ray_start  = (const float*)d_in[0];
    const float* ray_dir    = (const float*)d_in[1];
    const float* depth      = (const float*)d_in[2];
    const float* dists      = (const float*)d_in[3];
    const int*   vidx       = (const int*)d_in[4];
    const float* vcol       = (const float*)d_in[5];
    const float* W1         = (const float*)d_in[6];
    const float* b1         = (const float*)d_in[7];
    const float* w_sigma    = (const float*)d_in[8];
    const float* b_sigma    = (const float*)d_in[9];
    const float* W_tex      = (const float*)d_in[10];
    const float* b_tex      = (const float*)d_in[11];

    const int N = in_sizes[0] / 3;       // 4096 rays
    float* out        = (float*)d_out;
    float* out_colors = out;
    float* out_depths = out + (size_t)N * 3;
    float* out_missed = out + (size_t)N * 3 + N;
    float* out_probs  = out + (size_t)N * 3 + 2 * (size_t)N;

    volrend_kernel<<<N, 256, 0, stream>>>(
        ray_start, ray_dir, depth, dists, vidx, vcol,
        W1, b1, w_sigma, b_sigma, W_tex, b_tex,
        out_colors, out_depths, out_missed, out_probs);
}

// Round 9
// 19.392 us; speedup vs baseline: 2.7506x; 1.0853x over previous
//
#include <hip/hip_runtime.h>

#define K_SAMP 256
#define D_HID 64
#define SCALER_FE 7.0f

typedef _Float16 half8  __attribute__((ext_vector_type(8)));
typedef __fp16   fp16x2 __attribute__((ext_vector_type(2)));
typedef float    f32x4  __attribute__((ext_vector_type(4)));

union H8U4 { half8 h; uint4 u; };
union H8P  { fp16x2 h2[4]; half8 h8; };

__device__ __forceinline__ half8 h8zero() {
    half8 a;
    #pragma unroll
    for (int j = 0; j < 8; ++j) a[j] = (_Float16)0.f;
    return a;
}

// DPP-based add: x + (x shifted by dpp_ctrl), masked rows keep x (identity 0).
#define DPP_ADD(x, ctrl, rowmask)                                              \
    (x) += __int_as_float(__builtin_amdgcn_update_dpp(                         \
        0, __float_as_int(x), (ctrl), (rowmask), 0xf, false))

// Inclusive 64-lane scan (canonical GCN sequence, VALU-only, no LDS).
__device__ __forceinline__ float dpp_scan_incl(float x) {
    DPP_ADD(x, 0x111, 0xf);   // row_shr:1
    DPP_ADD(x, 0x112, 0xf);   // row_shr:2
    DPP_ADD(x, 0x114, 0xf);   // row_shr:4
    DPP_ADD(x, 0x118, 0xf);   // row_shr:8
    DPP_ADD(x, 0x142, 0xa);   // row_bcast15 -> rows 1,3
    DPP_ADD(x, 0x143, 0xc);   // row_bcast31 -> rows 2,3
    return x;                 // lane 63 holds the 64-lane total
}

// Block = 4 waves = 4 rays; each wave owns one full ray (16 MFMA tiles of 16).
// Wave 0 stages ray-independent f16 weight fragments in LDS (one barrier);
// afterwards waves are fully independent: same-wave LDS round-trip for the
// MFMA outputs (lgkmcnt, no barrier), DPP scan/reduce (no ds_bpermute),
// epilogue inputs (incl. voxel gather) prefetched before the MFMA loop.
__global__ __launch_bounds__(256, 4)
void volrend_kernel(const float* __restrict__ ray_start,
                    const float* __restrict__ ray_dir,
                    const float* __restrict__ depth,
                    const float* __restrict__ dists,
                    const int*   __restrict__ vidx,
                    const float* __restrict__ vcol_tab,
                    const float* __restrict__ W1,
                    const float* __restrict__ b1,
                    const float* __restrict__ w_sigma,
                    const float* __restrict__ b_sigma,
                    const float* __restrict__ W_tex,
                    const float* __restrict__ b_tex,
                    float* __restrict__ out_colors,
                    float* __restrict__ out_depths,
                    float* __restrict__ out_missed,
                    float* __restrict__ out_probs) {
    __shared__ uint4 sFrag[6 * 64];          // 6 KB: a1[0..3], a2a, a2b per lane
    __shared__ float sOut[4][K_SAMP][4];     // 16 KB: per-wave {sigma,t0,t1,t2}

    const int tid  = threadIdx.x;
    const int lane = tid & 63;
    const int wv   = tid >> 6;
    const int ray  = __builtin_amdgcn_readfirstlane(blockIdx.x * 4 + wv);
    const int m    = lane & 15;              // sample index inside MFMA tile
    const int g    = lane >> 4;              // K-slice lane group

    // --- wave 0: build fragments into LDS (ray-independent, lane-indexed) ---
    if (tid < 64) {
        #pragma unroll
        for (int tt = 0; tt < 4; ++tt) {
            const int dim = 8 * (m >> 2) + (m & 3) + 4 * (tt & 1) + 32 * (tt >> 1);
            half8 a = h8zero();
            if (g == 0) {
                #pragma unroll
                for (int j = 0; j < 6; ++j) a[j] = (_Float16)W1[j * D_HID + dim];
                a[6] = (_Float16)b1[dim];
            }
            H8U4 c; c.h = a;
            sFrag[tt * 64 + lane] = c.u;
        }
        half8 a2a = h8zero(), a2b = h8zero();
        if (m < 4) {
            const int c = (m >= 1) ? (m - 1) : 0;
            #pragma unroll
            for (int j = 0; j < 8; ++j) {
                const int d = 8 * g + j;
                a2a[j] = (_Float16)((m == 0) ? w_sigma[d]      : W_tex[d * 3 + c]);
                a2b[j] = (_Float16)((m == 0) ? w_sigma[d + 32] : W_tex[(d + 32) * 3 + c]);
            }
        }
        H8U4 ca; ca.h = a2a; sFrag[4 * 64 + lane] = ca.u;
        H8U4 cb; cb.h = a2b; sFrag[5 * 64 + lane] = cb.u;
    }

    // --- per-ray uniforms (wave-uniform -> scalar loads) ---
    const float rs0 = ray_start[ray * 3 + 0];
    const float rs1 = ray_start[ray * 3 + 1];
    const float rs2 = ray_start[ray * 3 + 2];
    const float rd0 = ray_dir[ray * 3 + 0];
    const float rd1 = ray_dir[ray * 3 + 1];
    const float rd2 = ray_dir[ray * 3 + 2];
    const float bs  = b_sigma[0];
    const float bt0 = b_tex[0], bt1 = b_tex[1], bt2 = b_tex[2];

    // --- prefetch epilogue inputs (issue before MFMA loop; latency hides) ---
    const size_t rayBase = (size_t)ray * K_SAMP;
    const float4 dep4 = ((const float4*)(depth + rayBase))[lane];
    const float4 dst4 = ((const float4*)(dists + rayBase))[lane];
    const int4   vi4  = ((const int4*)(vidx  + rayBase))[lane];
    const int via[4] = {vi4.x, vi4.y, vi4.z, vi4.w};
    bool  msk[4];
    float vc[4][3];
    #pragma unroll
    for (int s = 0; s < 4; ++s) {
        msk[s] = (via[s] != -1);
        const int b = (msk[s] ? via[s] : 0) * 3;
        vc[s][0] = vcol_tab[b + 0];
        vc[s][1] = vcol_tab[b + 1];
        vc[s][2] = vcol_tab[b + 2];
    }

    __syncthreads();                         // frag staging visible to all waves

    half8 a1[4];
    #pragma unroll
    for (int tt = 0; tt < 4; ++tt) { H8U4 c; c.u = sFrag[tt * 64 + lane]; a1[tt] = c.h; }
    H8U4 ca; ca.u = sFrag[4 * 64 + lane]; const half8 a2a = ca.h;
    H8U4 cb; cb.u = sFrag[5 * 64 + lane]; const half8 a2b = cb.h;

    f32x4 oinit = {0.f, 0.f, 0.f, 0.f};
    if (g == 0) { oinit[0] = bs; oinit[1] = bt0; oinit[2] = bt1; oinit[3] = bt2; }
    const f32x4 zero4 = {0.f, 0.f, 0.f, 0.f};

    const fp16x2 hc12 = __builtin_amdgcn_cvt_pkrtz(rd1, rd2);
    const fp16x2 hc3  = __builtin_amdgcn_cvt_pkrtz(1.0f, 0.0f);

    // --- 16 sample-tiles of 16 (whole ray, this wave only) ---
    #pragma unroll 4
    for (int t = 0; t < 16; ++t) {
        const float dpt = depth[rayBase + 16 * t + m];
        const float fx = fmaf(rd0, dpt, rs0);
        const float fy = fmaf(rd1, dpt, rs1);
        const float fz = fmaf(rd2, dpt, rs2);
        H8P bb;
        bb.h2[0] = __builtin_amdgcn_cvt_pkrtz(fx, fy);
        bb.h2[1] = __builtin_amdgcn_cvt_pkrtz(fz, rd0);
        bb.h2[2] = hc12;
        bb.h2[3] = hc3;
        const f32x4 h0 = __builtin_amdgcn_mfma_f32_16x16x32_f16(a1[0], bb.h8, zero4, 0, 0, 0);
        const f32x4 h1 = __builtin_amdgcn_mfma_f32_16x16x32_f16(a1[1], bb.h8, zero4, 0, 0, 0);
        const f32x4 h2 = __builtin_amdgcn_mfma_f32_16x16x32_f16(a1[2], bb.h8, zero4, 0, 0, 0);
        const f32x4 h3 = __builtin_amdgcn_mfma_f32_16x16x32_f16(a1[3], bb.h8, zero4, 0, 0, 0);

        H8P p2a, p2b;
        p2a.h2[0] = __builtin_amdgcn_cvt_pkrtz(fmaxf(h0[0], 0.f), fmaxf(h0[1], 0.f));
        p2a.h2[1] = __builtin_amdgcn_cvt_pkrtz(fmaxf(h0[2], 0.f), fmaxf(h0[3], 0.f));
        p2a.h2[2] = __builtin_amdgcn_cvt_pkrtz(fmaxf(h1[0], 0.f), fmaxf(h1[1], 0.f));
        p2a.h2[3] = __builtin_amdgcn_cvt_pkrtz(fmaxf(h1[2], 0.f), fmaxf(h1[3], 0.f));
        p2b.h2[0] = __builtin_amdgcn_cvt_pkrtz(fmaxf(h2[0], 0.f), fmaxf(h2[1], 0.f));
        p2b.h2[1] = __builtin_amdgcn_cvt_pkrtz(fmaxf(h2[2], 0.f), fmaxf(h2[3], 0.f));
        p2b.h2[2] = __builtin_amdgcn_cvt_pkrtz(fmaxf(h3[0], 0.f), fmaxf(h3[1], 0.f));
        p2b.h2[3] = __builtin_amdgcn_cvt_pkrtz(fmaxf(h3[2], 0.f), fmaxf(h3[3], 0.f));

        f32x4 o = oinit;
        o = __builtin_amdgcn_mfma_f32_16x16x32_f16(a2a, p2a.h8, o, 0, 0, 0);
        o = __builtin_amdgcn_mfma_f32_16x16x32_f16(a2b, p2b.h8, o, 0, 0, 0);

        if (g == 0) {
            *(float4*)&sOut[wv][16 * t + m][0] = make_float4(o[0], o[1], o[2], o[3]);
        }
    }

    // --- epilogue: same-wave LDS read-back (lgkmcnt dependency, no barrier) ---
    const float depa[4] = {dep4.x, dep4.y, dep4.z, dep4.w};
    const float dsta[4] = {dst4.x, dst4.y, dst4.z, dst4.w};
    float fe[4], tA[4], tB[4], tC[4];
    #pragma unroll
    for (int s = 0; s < 4; ++s) {
        const float4 r4 = *(const float4*)&sOut[wv][4 * lane + s][0];
        if (msk[s]) {
            fe[s] = fmaxf(r4.x, 0.f) * dsta[s] * SCALER_FE;
            tA[s] = r4.y + vc[s][0];
            tB[s] = r4.z + vc[s][1];
            tC[s] = r4.w + vc[s][2];
        } else {
            fe[s] = 0.f; tA[s] = 0.f; tB[s] = 0.f; tC[s] = 0.f;
        }
    }

    // exclusive prefix over the ray: thread-local + DPP wave scan
    const float T = fe[0] + fe[1] + fe[2] + fe[3];
    const float x = dpp_scan_incl(T);
    const float e0 = x - T;
    const float e1 = e0 + fe[0];
    const float e2 = e1 + fe[1];
    const float e3 = e2 + fe[2];

    const float p0 = (1.0f - __expf(-fe[0])) * __expf(-e0);
    const float p1 = (1.0f - __expf(-fe[1])) * __expf(-e1);
    const float p2 = (1.0f - __expf(-fe[2])) * __expf(-e2);
    const float p3 = (1.0f - __expf(-fe[3])) * __expf(-e3);

    ((float4*)(out_probs + rayBase))[lane] = make_float4(p0, p1, p2, p3);

    // 5 reductions via DPP scans; lane 63 holds totals and writes outputs
    float sp = dpp_scan_incl(p0 + p1 + p2 + p3);
    float sd = dpp_scan_incl(depa[0] * p0 + depa[1] * p1 + depa[2] * p2 + depa[3] * p3);
    float c0 = dpp_scan_incl(tA[0] * p0 + tA[1] * p1 + tA[2] * p2 + tA[3] * p3);
    float c1 = dpp_scan_incl(tB[0] * p0 + tB[1] * p1 + tB[2] * p2 + tB[3] * p3);
    float c2 = dpp_scan_incl(tC[0] * p0 + tC[1] * p1 + tC[2] * p2 + tC[3] * p3);
    if (lane == 63) {
        out_colors[ray * 3 + 0] = c0;
        out_colors[ray * 3 + 1] = c1;
        out_colors[ray * 3 + 2] = c2;
        out_depths[ray] = sd;
        out_missed[ray] = 1.0f - sp;
    }
}

extern "C" void kernel_launch(void* const* d_in, const int* in_sizes, int n_in,
                              void* d_out, int out_size, void* d_ws, size_t ws_size,
                              hipStream_t stream) {
    const float* ray_start  = (const float*)d_in[0];
    const float* ray_dir    = (const float*)d_in[1];
    const float* depth      = (const float*)d_in[2];
    const float* dists      = (const float*)d_in[3];
    const int*   vidx       = (const int*)d_in[4];
    const float* vcol       = (const float*)d_in[5];
    const float* W1         = (const float*)d_in[6];
    const float* b1         = (const float*)d_in[7];
    const float* w_sigma    = (const float*)d_in[8];
    const float* b_sigma    = (const float*)d_in[9];
    const float* W_tex      = (const float*)d_in[10];
    const float* b_tex      = (const float*)d_in[11];

    const int N = in_sizes[0] / 3;       // 4096 rays
    float* out        = (float*)d_out;
    float* out_colors = out;
    float* out_depths = out + (size_t)N * 3;
    float* out_missed = out + (size_t)N * 3 + N;
    float* out_probs  = out + (size_t)N * 3 + 2 * (size_t)N;

    volrend_kernel<<<N / 4, 256, 0, stream>>>(
        ray_start, ray_dir, depth, dists, vidx, vcol,
        W1, b1, w_sigma, b_sigma, W_tex, b_tex,
        out_colors, out_depths, out_missed, out_probs);
}